// Round 6
// baseline (779.586 us; speedup 1.0000x reference)
//
#include <hip/hip_runtime.h>

// Problem constants: N=2048, L=4096, M=512, P=512
#define NN 2048
#define LL 4096
#define MM 512
#define PP 512

#define NBLOCKS 256
#define NTHREADS 1024
#define NWAVES (NBLOCKS * 16)
#define SWEEPS 13      // tanh-Jacobi sweeps after the eps0 = tanh(a/Lam) init
#define RICH 10        // Richardson iterations for E x = b

typedef unsigned short ushort_t;
typedef unsigned int   uint_t;

__device__ __forceinline__ float wave_reduce_sum(float v) {
#pragma unroll
    for (int off = 32; off > 0; off >>= 1) v += __shfl_xor(v, off, 64);
    return v;
}

__device__ __forceinline__ ushort_t f2bf(float f) {  // RNE float->bf16
    uint_t x = __float_as_uint(f);
    uint_t r = ((x >> 16) & 1u) + 0x7fffu;
    return (ushort_t)((x + r) >> 16);
}
__device__ __forceinline__ float bflo(uint_t w) { return __uint_as_float(w << 16); }
__device__ __forceinline__ float bfhi(uint_t w) { return __uint_as_float(w & 0xffff0000u); }

struct KArgs {
    const float *x, *u, *C1, *D11, *D12, *Lam, *F, *B1, *B2, *E, *C2, *D21, *D22;
    const float *bv, *bx, *bu;
    const int* t;
    float* yout; float* xout;
    ushort_t* D11b; ushort_t* Gb;
    float *a, *epsA, *epsB, *q, *y0, *b, *xa, *xb;
    int* counter; int* gen;
    int use_bf;
};

// Grid barrier (generation counter). All blocks co-resident (cooperative launch).
__device__ __forceinline__ void gsync(int* counter, int* gen, int target) {
    __syncthreads();
    if (threadIdx.x == 0) {
        __threadfence();
        int prev = __hip_atomic_fetch_add(counter, 1, __ATOMIC_ACQ_REL,
                                          __HIP_MEMORY_SCOPE_AGENT);
        if (prev == NBLOCKS - 1) {
            __hip_atomic_store(counter, 0, __ATOMIC_RELAXED, __HIP_MEMORY_SCOPE_AGENT);
            __hip_atomic_fetch_add(gen, 1, __ATOMIC_RELEASE, __HIP_MEMORY_SCOPE_AGENT);
        } else {
            while (__hip_atomic_load(gen, __ATOMIC_ACQUIRE,
                                     __HIP_MEMORY_SCOPE_AGENT) < target)
                __builtin_amdgcn_s_sleep(2);
        }
        __threadfence();
    }
    __syncthreads();
}

__global__ void init_sync(int* counter, int* gen) {
    if (threadIdx.x == 0) { *counter = 0; *gen = 0; }
}

__device__ __forceinline__ float dot_f32(const float* __restrict__ Mrow,
                                         const float* __restrict__ v,
                                         int n, int lane) {
    const float4* Mr = reinterpret_cast<const float4*>(Mrow);
    const float4* V  = reinterpret_cast<const float4*>(v);
    float acc = 0.f;
    int nv = n >> 2;
    for (int c = lane; c < nv; c += 64) {
        float4 m = Mr[c], vv = V[c];
        acc = fmaf(m.x, vv.x, acc); acc = fmaf(m.y, vv.y, acc);
        acc = fmaf(m.z, vv.z, acc); acc = fmaf(m.w, vv.w, acc);
    }
    return acc;
}

__global__ __launch_bounds__(1024, 2) void fused_kernel(KArgs A) {
    const int warp = threadIdx.x >> 6;
    const int lane = threadIdx.x & 63;
    const int W    = blockIdx.x * 16 + warp;
    __shared__ float part[16];
    int bar = 0;

    const float decay = __powf(0.95f, (float)(*A.t));

    // ---------------- Phase A: independent GEMVs + bf16 conversions ----------
    const int NT_A = A.use_bf ? (6656 + LL + NN) : 6656;
    for (int tt = W; tt < NT_A; tt += NWAVES) {
        if (tt < LL) {                       // a[r] = C1[r]·x + D12[r]·u + decay*bv
            int r = tt;
            float acc = dot_f32(A.C1 + (size_t)r * NN, A.x, NN, lane)
                      + dot_f32(A.D12 + (size_t)r * MM, A.u, MM, lane);
            acc = wave_reduce_sum(acc);
            if (lane == 0) {
                float av = fmaf(decay, A.bv[r], acc);
                A.a[r] = av;
                A.epsA[r] = tanhf(av / A.Lam[r]);
            }
        } else if (tt < LL + NN) {           // q[r] = F[r]·x + B2[r]·u + decay*bx
            int r = tt - LL;
            float acc = dot_f32(A.F + (size_t)r * NN, A.x, NN, lane)
                      + dot_f32(A.B2 + (size_t)r * MM, A.u, MM, lane);
            acc = wave_reduce_sum(acc);
            if (lane == 0) A.q[r] = fmaf(decay, A.bx[r], acc);
        } else if (tt < 6656) {              // y0[r] = C2[r]·x + D22[r]·u + decay*bu
            int r = tt - (LL + NN);
            float acc = dot_f32(A.C2 + (size_t)r * NN, A.x, NN, lane)
                      + dot_f32(A.D22 + (size_t)r * MM, A.u, MM, lane);
            acc = wave_reduce_sum(acc);
            if (lane == 0) A.y0[r] = fmaf(decay, A.bu[r], acc);
        } else if (tt < 6656 + LL) {         // D11 row -> bf16 (strict tril, zero-padded)
            int r = ((tt - 6656) * 2731) & (LL - 1);
            const float4* Dr = reinterpret_cast<const float4*>(A.D11 + (size_t)r * LL);
            uint4* Ob = reinterpret_cast<uint4*>(A.D11b + (size_t)r * LL);
            int nh8 = (r + 7) >> 3;
            for (int c = lane; c < nh8; c += 64) {
                float4 f0 = Dr[2 * c], f1 = Dr[2 * c + 1];
                int base = c << 3;
                ushort_t s0 = (base + 0 < r) ? f2bf(f0.x) : (ushort_t)0;
                ushort_t s1 = (base + 1 < r) ? f2bf(f0.y) : (ushort_t)0;
                ushort_t s2 = (base + 2 < r) ? f2bf(f0.z) : (ushort_t)0;
                ushort_t s3 = (base + 3 < r) ? f2bf(f0.w) : (ushort_t)0;
                ushort_t s4 = (base + 4 < r) ? f2bf(f1.x) : (ushort_t)0;
                ushort_t s5 = (base + 5 < r) ? f2bf(f1.y) : (ushort_t)0;
                ushort_t s6 = (base + 6 < r) ? f2bf(f1.z) : (ushort_t)0;
                ushort_t s7 = (base + 7 < r) ? f2bf(f1.w) : (ushort_t)0;
                uint4 o;
                o.x = (uint_t)s0 | ((uint_t)s1 << 16);
                o.y = (uint_t)s2 | ((uint_t)s3 << 16);
                o.z = (uint_t)s4 | ((uint_t)s5 << 16);
                o.w = (uint_t)s6 | ((uint_t)s7 << 16);
                Ob[c] = o;
            }
        } else {                             // G = I - E  -> bf16
            int r = tt - (6656 + LL);
            const float4* Er = reinterpret_cast<const float4*>(A.E + (size_t)r * NN);
            uint4* Ob = reinterpret_cast<uint4*>(A.Gb + (size_t)r * NN);
            for (int c = lane; c < NN / 8; c += 64) {
                float4 f0 = Er[2 * c], f1 = Er[2 * c + 1];
                int base = c << 3;
                float g0 = ((base + 0) == r ? 1.f : 0.f) - f0.x;
                float g1 = ((base + 1) == r ? 1.f : 0.f) - f0.y;
                float g2 = ((base + 2) == r ? 1.f : 0.f) - f0.z;
                float g3 = ((base + 3) == r ? 1.f : 0.f) - f0.w;
                float g4 = ((base + 4) == r ? 1.f : 0.f) - f1.x;
                float g5 = ((base + 5) == r ? 1.f : 0.f) - f1.y;
                float g6 = ((base + 6) == r ? 1.f : 0.f) - f1.z;
                float g7 = ((base + 7) == r ? 1.f : 0.f) - f1.w;
                uint4 o;
                o.x = (uint_t)f2bf(g0) | ((uint_t)f2bf(g1) << 16);
                o.y = (uint_t)f2bf(g2) | ((uint_t)f2bf(g3) << 16);
                o.z = (uint_t)f2bf(g4) | ((uint_t)f2bf(g5) << 16);
                o.w = (uint_t)f2bf(g6) | ((uint_t)f2bf(g7) << 16);
                Ob[c] = o;
            }
        }
    }
    gsync(A.counter, A.gen, ++bar);

    // ---------------- Phase B: nonlinear Jacobi sweeps -----------------------
    const int myrow = (W * 2731) & (LL - 1);     // bijection, load balance
    const float a_r   = A.a[myrow];
    const float lam_r = A.Lam[myrow];
    const int nh8 = (myrow + 7) >> 3;
    const int nf4 = (myrow + 3) >> 2;
    const uint4*  Db = reinterpret_cast<const uint4*>(A.D11b + (size_t)myrow * LL);
    const float4* Df = reinterpret_cast<const float4*>(A.D11 + (size_t)myrow * LL);

    for (int s = 0; s < SWEEPS; ++s) {
        const float* ein = (s & 1) ? A.epsB : A.epsA;
        float*      eout = (s & 1) ? A.epsA : A.epsB;
        float acc = 0.f;
        const float4* Ev = reinterpret_cast<const float4*>(ein);
        if (A.use_bf) {
            for (int c = lane; c < nh8; c += 64) {
                uint4 w = Db[c];
                float4 e0 = Ev[2 * c], e1 = Ev[2 * c + 1];
                acc = fmaf(bflo(w.x), e0.x, acc); acc = fmaf(bfhi(w.x), e0.y, acc);
                acc = fmaf(bflo(w.y), e0.z, acc); acc = fmaf(bfhi(w.y), e0.w, acc);
                acc = fmaf(bflo(w.z), e1.x, acc); acc = fmaf(bfhi(w.z), e1.y, acc);
                acc = fmaf(bflo(w.w), e1.z, acc); acc = fmaf(bfhi(w.w), e1.w, acc);
            }
        } else {
            for (int c = lane; c < nf4; c += 64) {
                float4 m = Df[c], vv = Ev[c];
                acc = fmaf(m.x, vv.x, acc); acc = fmaf(m.y, vv.y, acc);
                acc = fmaf(m.z, vv.z, acc); acc = fmaf(m.w, vv.w, acc);
            }
        }
        acc = wave_reduce_sum(acc);
        if (lane == 0) eout[myrow] = tanhf((a_r + acc) / lam_r);
        gsync(A.counter, A.gen, ++bar);
    }
    const float* eps = (SWEEPS & 1) ? A.epsB : A.epsA;

    // ---------------- Phase C: y and b = B1 eps + q ---------------------------
    for (int tt = W; tt < PP + NN; tt += NWAVES) {
        if (tt < PP) {
            int r = tt;
            float acc = dot_f32(A.D21 + (size_t)r * LL, eps, LL, lane);
            acc = wave_reduce_sum(acc);
            if (lane == 0) A.yout[r] = A.y0[r] + acc;
        } else {
            int r = tt - PP;
            float acc = dot_f32(A.B1 + (size_t)r * LL, eps, LL, lane);
            acc = wave_reduce_sum(acc);
            if (lane == 0) A.b[r] = A.q[r] + acc;
        }
    }
    gsync(A.counter, A.gen, ++bar);

    // ---------------- Phase D: Richardson, 2 waves per row --------------------
    const int drow  = W >> 1;
    const int dhalf = W & 1;
    const float b_r = A.b[drow];
    for (int k = 0; k < RICH; ++k) {
        const float* xin = (k == 0) ? A.b : ((k & 1) ? A.xa : A.xb);
        float*       xo  = (k == RICH - 1) ? A.xout : ((k & 1) ? A.xb : A.xa);
        float acc = 0.f;
        if (A.use_bf) {   // x_{k+1} = b + G x_k  (G = I - E, bf16)
            const uint4* Gr = reinterpret_cast<const uint4*>(A.Gb + (size_t)drow * NN);
            const float4* Xv = reinterpret_cast<const float4*>(xin);
            int c0 = dhalf * (NN / 16);   // 128 chunks per half
            for (int c = lane; c < NN / 16; c += 64) {
                uint4 w = Gr[c0 + c];
                float4 e0 = Xv[2 * (c0 + c)], e1 = Xv[2 * (c0 + c) + 1];
                acc = fmaf(bflo(w.x), e0.x, acc); acc = fmaf(bfhi(w.x), e0.y, acc);
                acc = fmaf(bflo(w.y), e0.z, acc); acc = fmaf(bfhi(w.y), e0.w, acc);
                acc = fmaf(bflo(w.z), e1.x, acc); acc = fmaf(bfhi(w.z), e1.y, acc);
                acc = fmaf(bflo(w.w), e1.z, acc); acc = fmaf(bfhi(w.w), e1.w, acc);
            }
        } else {          // x_{k+1} = x_k + b - E x_k (fp32)
            const float4* Er = reinterpret_cast<const float4*>(A.E + (size_t)drow * NN);
            const float4* Xv = reinterpret_cast<const float4*>(xin);
            int c0 = dhalf * (NN / 8);    // 256 float4 per half
            for (int c = lane; c < NN / 8; c += 64) {
                float4 m = Er[c0 + c], vv = Xv[c0 + c];
                acc = fmaf(m.x, vv.x, acc); acc = fmaf(m.y, vv.y, acc);
                acc = fmaf(m.z, vv.z, acc); acc = fmaf(m.w, vv.w, acc);
            }
        }
        acc = wave_reduce_sum(acc);
        if (lane == 0) part[warp] = acc;
        __syncthreads();
        if (lane == 0 && (warp & 1) == 0) {
            float s = part[warp] + part[warp + 1];
            xo[drow] = A.use_bf ? (b_r + s) : (xin[drow] + b_r - s);
        }
        if (k < RICH - 1) gsync(A.counter, A.gen, ++bar);
    }
}

extern "C" void kernel_launch(void* const* d_in, const int* in_sizes, int n_in,
                              void* d_out, int out_size, void* d_ws, size_t ws_size,
                              hipStream_t stream) {
    KArgs A;
    A.x   = (const float*)d_in[0];
    A.u   = (const float*)d_in[1];
    A.C1  = (const float*)d_in[2];
    A.D11 = (const float*)d_in[3];
    A.D12 = (const float*)d_in[4];
    A.Lam = (const float*)d_in[5];
    A.F   = (const float*)d_in[6];
    A.B1  = (const float*)d_in[7];
    A.B2  = (const float*)d_in[8];
    A.E   = (const float*)d_in[9];
    A.C2  = (const float*)d_in[10];
    A.D21 = (const float*)d_in[11];
    A.D22 = (const float*)d_in[12];
    A.bv  = (const float*)d_in[13];
    A.bx  = (const float*)d_in[14];
    A.bu  = (const float*)d_in[15];
    A.t   = (const int*)d_in[16];
    A.yout = (float*)d_out;
    A.xout = (float*)d_out + PP;

    // ws layout: [D11b bf16 32MB][Gb bf16 8MB][vectors ~76KB][2 sync ints]
    const size_t bf_bytes = (size_t)LL * LL * 2 + (size_t)NN * NN * 2;
    const size_t vec_floats = 4096 * 3 + 2048 * 4 + 512;  // a,epsA,epsB,q,b,xa,xb,y0
    const size_t need = bf_bytes + vec_floats * 4 + 64;
    int use_bf = (ws_size >= need) ? 1 : 0;

    char* base = (char*)d_ws;
    A.D11b = (ushort_t*)base;
    A.Gb   = (ushort_t*)(base + (size_t)LL * LL * 2);
    float* vecs = use_bf ? (float*)(base + bf_bytes) : (float*)base;
    A.a    = vecs;
    A.epsA = vecs + 4096;
    A.epsB = vecs + 8192;
    A.q    = vecs + 12288;
    A.y0   = vecs + 14336;
    A.b    = vecs + 14848;
    A.xa   = vecs + 16896;
    A.xb   = vecs + 18944;
    int* sync_ints = (int*)(vecs + 20992);
    A.counter = sync_ints;
    A.gen     = sync_ints + 1;
    A.use_bf  = use_bf;

    init_sync<<<1, 64, 0, stream>>>(A.counter, A.gen);

    void* params[] = { &A };
    hipLaunchCooperativeKernel((const void*)fused_kernel, dim3(NBLOCKS),
                               dim3(NTHREADS), params, 0, stream);
}

// Round 7
// 275.239 us; speedup vs baseline: 2.8324x; 2.8324x over previous
//
#include <hip/hip_runtime.h>

// Problem constants: N=2048, L=4096, M=512, P=512
#define NN 2048
#define LL 4096
#define MM 512
#define PP 512

#define NBLOCKS 256
#define NTHREADS 1024
#define NWAVES (NBLOCKS * 16)
#define SWEEPS 13      // tanh-Jacobi sweeps after eps0 = tanh(a/Lam)
#define RICH 10        // Richardson iterations for E x = b

typedef unsigned short ushort_t;
typedef unsigned int   uint_t;

#define ALOAD(p)     __hip_atomic_load((p), __ATOMIC_RELAXED, __HIP_MEMORY_SCOPE_AGENT)
#define ASTORE(p, v) __hip_atomic_store((p), (v), __ATOMIC_RELAXED, __HIP_MEMORY_SCOPE_AGENT)

__device__ __forceinline__ float wave_reduce_sum(float v) {
#pragma unroll
    for (int off = 32; off > 0; off >>= 1) v += __shfl_xor(v, off, 64);
    return v;
}

__device__ __forceinline__ ushort_t f2bf(float f) {  // RNE float->bf16
    uint_t x = __float_as_uint(f);
    uint_t r = ((x >> 16) & 1u) + 0x7fffu;
    return (ushort_t)((x + r) >> 16);
}
__device__ __forceinline__ uint_t pack2(float lo, float hi) {
    return (uint_t)f2bf(lo) | ((uint_t)f2bf(hi) << 16);
}
__device__ __forceinline__ float bflo(uint_t w) { return __uint_as_float(w << 16); }
__device__ __forceinline__ float bfhi(uint_t w) { return __uint_as_float(w & 0xffff0000u); }
__device__ __forceinline__ int swz(int j) { return j ^ ((j >> 3) & 7); }

struct KArgs {
    const float *x, *u, *C1, *D11, *D12, *Lam, *F, *B1, *B2, *E, *C2, *D21, *D22;
    const float *bv, *bx, *bu;
    const int* t;
    float* yout; float* xout;
    ushort_t* D11b; ushort_t* Gb;
    float *epsA, *epsB, *q, *y0, *b, *xa, *xb;
    int* counter;
    int use_bf;
};

// Grid barrier: monotonic relaxed counter. NO acquire/release fences (no L2
// inv/wb). Coherence for shared data comes from sc1 (agent-scope relaxed
// atomic) loads/stores on that data itself. __syncthreads drains vmcnt for
// every wave before thread 0 signals.
__device__ __forceinline__ void gsync(int* counter, int bar) {
    __syncthreads();
    if (threadIdx.x == 0) {
        __hip_atomic_fetch_add(counter, 1, __ATOMIC_RELAXED, __HIP_MEMORY_SCOPE_AGENT);
        while (__hip_atomic_load(counter, __ATOMIC_RELAXED, __HIP_MEMORY_SCOPE_AGENT)
               < bar * NBLOCKS)
            __builtin_amdgcn_s_sleep(2);
    }
    __syncthreads();
}

__global__ void init_sync(int* counter) {
    if (threadIdx.x == 0) *counter = 0;
}

__device__ __forceinline__ float dot_f32(const float* __restrict__ Mrow,
                                         const float* __restrict__ v,
                                         int n, int lane) {
    const float4* Mr = reinterpret_cast<const float4*>(Mrow);
    const float4* V  = reinterpret_cast<const float4*>(v);
    float acc = 0.f;
    int nv = n >> 2;
    for (int c = lane; c < nv; c += 64) {
        float4 m = Mr[c], vv = V[c];
        acc = fmaf(m.x, vv.x, acc); acc = fmaf(m.y, vv.y, acc);
        acc = fmaf(m.z, vv.z, acc); acc = fmaf(m.w, vv.w, acc);
    }
    return acc;
}

// dot of fp32 global row against LDS-staged swizzled vector
__device__ __forceinline__ float dot_lds_f32(const float* __restrict__ Mrow,
                                             const float4* evec, int nf4, int lane) {
    const float4* Mr = reinterpret_cast<const float4*>(Mrow);
    float acc = 0.f;
    for (int c = lane; c < nf4; c += 64) {
        float4 m = Mr[c];
        float4 e = evec[swz(c)];
        acc = fmaf(m.x, e.x, acc); acc = fmaf(m.y, e.y, acc);
        acc = fmaf(m.z, e.z, acc); acc = fmaf(m.w, e.w, acc);
    }
    return acc;
}

// dot of bf16 global row chunk [i0,i1) (uint4 = 8 bf16) against LDS vector
__device__ __forceinline__ float dot_lds_bf(const uint4* __restrict__ Db,
                                            const float4* evec, int i0, int i1, int lane) {
    float acc = 0.f;
    for (int c = i0 + lane; c < i1; c += 64) {
        uint4 w = Db[c];
        float4 e0 = evec[swz(2 * c)];
        float4 e1 = evec[swz(2 * c + 1)];
        acc = fmaf(bflo(w.x), e0.x, acc); acc = fmaf(bfhi(w.x), e0.y, acc);
        acc = fmaf(bflo(w.y), e0.z, acc); acc = fmaf(bfhi(w.y), e0.w, acc);
        acc = fmaf(bflo(w.z), e1.x, acc); acc = fmaf(bfhi(w.z), e1.y, acc);
        acc = fmaf(bflo(w.w), e1.z, acc); acc = fmaf(bfhi(w.w), e1.w, acc);
    }
    return acc;
}

__global__ __launch_bounds__(1024, 1) void fused_kernel(KArgs A) {
    const int tid  = threadIdx.x;
    const int warp = tid >> 6;
    const int lane = tid & 63;
    const int W    = blockIdx.x * 16 + warp;

    __shared__ float4 evec[1024];   // staged shared vector (swizzled)
    __shared__ float  part[16];

    int bar = 0;
    const float decay = __powf(0.95f, (float)(*A.t));

    // Row ownership: wave W owns row perm(W) for D11 convert AND all sweeps
    // (same wave => plain loads/stores are program-order coherent, L2-warm).
    const int myrow = (W * 2731) & (LL - 1);
    const int nh8 = (myrow + 7) >> 3;   // uint4-bf16 chunks covering [0,myrow)
    const int nf4 = (myrow + 3) >> 2;   // float4 chunks covering [0,myrow)
    float a_r = 0.f, lam_r = 1.f;

    // ---------------- Phase A: GEMVs + matrix conversions ----------------
    // tasks: [0,4096) a-row(+D11 cvt) | [4096,8192) G cvt half-rows |
    //        [8192,10240) q rows | [10240,10752) y0 rows
    for (int tt = W; tt < 10752; tt += NWAVES) {
        if (tt < LL) {
            const int r = myrow;             // tt == W on first pass
            float acc = dot_f32(A.C1 + (size_t)r * NN, A.x, NN, lane)
                      + dot_f32(A.D12 + (size_t)r * MM, A.u, MM, lane);
            acc = wave_reduce_sum(acc);      // butterfly: every lane has sum
            lam_r = A.Lam[r];
            a_r = fmaf(decay, A.bv[r], acc);
            if (lane == 0) ASTORE(&A.epsA[r], tanhf(a_r / lam_r));
            if (A.use_bf) {                  // convert my own D11 row (strict tril)
                const float4* Dr = reinterpret_cast<const float4*>(A.D11 + (size_t)r * LL);
                uint4* Ob = reinterpret_cast<uint4*>(A.D11b + (size_t)r * LL);
                for (int c = lane; c < nh8; c += 64) {
                    float4 f0 = Dr[2 * c], f1 = Dr[2 * c + 1];
                    uint4 o;
                    o.x = pack2(f0.x, f0.y); o.y = pack2(f0.z, f0.w);
                    o.z = pack2(f1.x, f1.y); o.w = pack2(f1.z, f1.w);
                    Ob[c] = o;               // cols >= r are exactly 0 in source
                }
            }
        } else if (tt < 8192) {
            if (A.use_bf) {                  // G = I - E, half-row owned by wave 2r+half
                const int idx = tt - 4096;   // == W on second pass
                const int r = idx >> 1, half = idx & 1;
                const float4* Er = reinterpret_cast<const float4*>(
                    A.E + (size_t)r * NN + half * 1024);
                uint4* Ob = reinterpret_cast<uint4*>(
                    A.Gb + (size_t)r * NN + half * 1024);
                for (int c = lane; c < 128; c += 64) {   // 128 uint4 per half
                    float4 f0 = Er[2 * c], f1 = Er[2 * c + 1];
                    const int g0 = half * 1024 + 8 * c;
                    float e[8] = {f0.x, f0.y, f0.z, f0.w, f1.x, f1.y, f1.z, f1.w};
                    uint_t wd[4];
#pragma unroll
                    for (int j2 = 0; j2 < 4; ++j2) {
                        float glo = ((g0 + 2 * j2)     == r ? 1.f : 0.f) - e[2 * j2];
                        float ghi = ((g0 + 2 * j2 + 1) == r ? 1.f : 0.f) - e[2 * j2 + 1];
                        wd[j2] = pack2(glo, ghi);
                    }
                    uint4 o; o.x = wd[0]; o.y = wd[1]; o.z = wd[2]; o.w = wd[3];
                    Ob[c] = o;
                }
            }
        } else if (tt < 10240) {
            const int r = tt - 8192;
            float acc = dot_f32(A.F + (size_t)r * NN, A.x, NN, lane)
                      + dot_f32(A.B2 + (size_t)r * MM, A.u, MM, lane);
            acc = wave_reduce_sum(acc);
            if (lane == 0) ASTORE(&A.q[r], fmaf(decay, A.bx[r], acc));
        } else {
            const int r = tt - 10240;
            float acc = dot_f32(A.C2 + (size_t)r * NN, A.x, NN, lane)
                      + dot_f32(A.D22 + (size_t)r * MM, A.u, MM, lane);
            acc = wave_reduce_sum(acc);
            if (lane == 0) ASTORE(&A.y0[r], fmaf(decay, A.bu[r], acc));
        }
    }
    gsync(A.counter, ++bar);

    // ---------------- Phase B: nonlinear Jacobi sweeps --------------------
    const uint4*  Db = reinterpret_cast<const uint4*>(A.D11b + (size_t)myrow * LL);
    const float4* Df = reinterpret_cast<const float4*>(A.D11 + (size_t)myrow * LL);

    for (int s = 0; s < SWEEPS; ++s) {
        const float* ein = (s & 1) ? A.epsB : A.epsA;
        float*      eout = (s & 1) ? A.epsA : A.epsB;
        {   // stage eps (4096 floats = 1024 chunks) via sc1 loads, swizzled
            const int j = tid;
            float4 v;
            v.x = ALOAD(ein + 4 * j);     v.y = ALOAD(ein + 4 * j + 1);
            v.z = ALOAD(ein + 4 * j + 2); v.w = ALOAD(ein + 4 * j + 3);
            evec[swz(j)] = v;
        }
        __syncthreads();
        float acc = A.use_bf ? dot_lds_bf(Db, evec, 0, nh8, lane)
                             : dot_lds_f32((const float*)Df, evec, nf4, lane);
        acc = wave_reduce_sum(acc);
        if (lane == 0) ASTORE(&eout[myrow], tanhf((a_r + acc) / lam_r));
        gsync(A.counter, ++bar);
    }
    const float* eps = (SWEEPS & 1) ? A.epsB : A.epsA;

    // ---------------- Phase C: y = D21 eps + y0 ; b = B1 eps + q ----------
    {   // stage final eps
        const int j = tid;
        float4 v;
        v.x = ALOAD(eps + 4 * j);     v.y = ALOAD(eps + 4 * j + 1);
        v.z = ALOAD(eps + 4 * j + 2); v.w = ALOAD(eps + 4 * j + 3);
        evec[swz(j)] = v;
    }
    __syncthreads();
    for (int tt = W; tt < PP + NN; tt += NWAVES) {
        if (tt < PP) {
            const int r = tt;
            float acc = dot_lds_f32(A.D21 + (size_t)r * LL, evec, 1024, lane);
            acc = wave_reduce_sum(acc);
            if (lane == 0) A.yout[r] = ALOAD(&A.y0[r]) + acc;
        } else {
            const int r = tt - PP;
            float acc = dot_lds_f32(A.B1 + (size_t)r * LL, evec, 1024, lane);
            acc = wave_reduce_sum(acc);
            if (lane == 0) ASTORE(&A.b[r], ALOAD(&A.q[r]) + acc);
        }
    }
    gsync(A.counter, ++bar);

    // ---------------- Phase D: Richardson (2 waves per row) ---------------
    const int drow = W >> 1, dhalf = W & 1;
    const float b_r = ALOAD(&A.b[drow]);
    const uint4*  Gr = reinterpret_cast<const uint4*>(A.Gb + (size_t)drow * NN);
    const float4* Er = reinterpret_cast<const float4*>(A.E + (size_t)drow * NN);

    for (int k = 0; k < RICH; ++k) {
        const float* xin = (k == 0) ? A.b : ((k & 1) ? A.xa : A.xb);
        float*       xo  = (k == RICH - 1) ? A.xout : ((k & 1) ? A.xb : A.xa);
        if (tid < 512) {   // stage xin (2048 floats = 512 chunks)
            const int j = tid;
            float4 v;
            v.x = ALOAD(xin + 4 * j);     v.y = ALOAD(xin + 4 * j + 1);
            v.z = ALOAD(xin + 4 * j + 2); v.w = ALOAD(xin + 4 * j + 3);
            evec[swz(j)] = v;
        }
        __syncthreads();
        float acc;
        if (A.use_bf) {     // x_{k+1} = b + G x_k   (G = I - E, bf16)
            acc = dot_lds_bf(Gr, evec, dhalf * 128, dhalf * 128 + 128, lane);
        } else {            // x_{k+1} = x_k + b - E x_k (fp32)
            acc = dot_lds_f32((const float*)Er + 0, evec, 0, lane);  // placeholder, below
            acc = 0.f;
            for (int c = dhalf * 256 + lane; c < dhalf * 256 + 256; c += 64) {
                float4 m = Er[c];
                float4 e = evec[swz(c)];
                acc = fmaf(m.x, e.x, acc); acc = fmaf(m.y, e.y, acc);
                acc = fmaf(m.z, e.z, acc); acc = fmaf(m.w, e.w, acc);
            }
        }
        acc = wave_reduce_sum(acc);
        if (lane == 0) part[warp] = acc;
        __syncthreads();
        if (lane == 0 && !(warp & 1)) {
            float s = part[warp] + part[warp + 1];
            float val = A.use_bf ? (b_r + s) : (ALOAD(&xin[drow]) + b_r - s);
            if (k == RICH - 1) xo[drow] = val;      // d_out: plain store
            else               ASTORE(&xo[drow], val);
        }
        if (k < RICH - 1) gsync(A.counter, ++bar);
    }
}

extern "C" void kernel_launch(void* const* d_in, const int* in_sizes, int n_in,
                              void* d_out, int out_size, void* d_ws, size_t ws_size,
                              hipStream_t stream) {
    KArgs A;
    A.x   = (const float*)d_in[0];
    A.u   = (const float*)d_in[1];
    A.C1  = (const float*)d_in[2];
    A.D11 = (const float*)d_in[3];
    A.D12 = (const float*)d_in[4];
    A.Lam = (const float*)d_in[5];
    A.F   = (const float*)d_in[6];
    A.B1  = (const float*)d_in[7];
    A.B2  = (const float*)d_in[8];
    A.E   = (const float*)d_in[9];
    A.C2  = (const float*)d_in[10];
    A.D21 = (const float*)d_in[11];
    A.D22 = (const float*)d_in[12];
    A.bv  = (const float*)d_in[13];
    A.bx  = (const float*)d_in[14];
    A.bu  = (const float*)d_in[15];
    A.t   = (const int*)d_in[16];
    A.yout = (float*)d_out;
    A.xout = (float*)d_out + PP;

    const size_t bf_bytes = (size_t)LL * LL * 2 + (size_t)NN * NN * 2;  // 40 MB
    const size_t vec_floats = 4096 * 2 + 2048 * 4 + 512;                // 16896
    const size_t need = bf_bytes + vec_floats * 4 + 64;
    const int use_bf = (ws_size >= need) ? 1 : 0;

    char* base = (char*)d_ws;
    A.D11b = (ushort_t*)base;
    A.Gb   = (ushort_t*)(base + (size_t)LL * LL * 2);
    float* vecs = use_bf ? (float*)(base + bf_bytes) : (float*)base;
    A.epsA = vecs;
    A.epsB = vecs + 4096;
    A.q    = vecs + 8192;
    A.y0   = vecs + 10240;
    A.b    = vecs + 10752;
    A.xa   = vecs + 12800;
    A.xb   = vecs + 14848;
    A.counter = (int*)(vecs + 16896);
    A.use_bf  = use_bf;

    init_sync<<<1, 64, 0, stream>>>(A.counter);

    void* params[] = { &A };
    hipLaunchCooperativeKernel((const void*)fused_kernel, dim3(NBLOCKS),
                               dim3(NTHREADS), params, 0, stream);
}

// Round 8
// 199.203 us; speedup vs baseline: 3.9135x; 1.3817x over previous
//
#include <hip/hip_runtime.h>

// Problem constants: N=2048, L=4096, M=512, P=512
#define NN 2048
#define LL 4096
#define MM 512
#define PP 512

#define NBLOCKS 256
#define NTHREADS 512
#define NWAVES (NBLOCKS * 8)   // 2048 waves
#define SWEEPS 13              // tanh-Jacobi sweeps after eps0 = tanh(a/Lam)
#define RICH 10                // Richardson iterations for E x = b

typedef unsigned short ushort_t;
typedef unsigned int   uint_t;

#define ALOADF(p)    __hip_atomic_load((p), __ATOMIC_RELAXED, __HIP_MEMORY_SCOPE_AGENT)
#define ALOADI(p)    __hip_atomic_load((p), __ATOMIC_RELAXED, __HIP_MEMORY_SCOPE_AGENT)
#define ASTOREF(p,v) __hip_atomic_store((p), (v), __ATOMIC_RELAXED, __HIP_MEMORY_SCOPE_AGENT)
#define ASTOREI(p,v) __hip_atomic_store((p), (v), __ATOMIC_RELAXED, __HIP_MEMORY_SCOPE_AGENT)

__device__ __forceinline__ float wave_reduce_sum(float v) {
#pragma unroll
    for (int off = 32; off > 0; off >>= 1) v += __shfl_xor(v, off, 64);
    return v;
}

__device__ __forceinline__ ushort_t f2bf(float f) {  // RNE float->bf16
    uint_t x = __float_as_uint(f);
    uint_t r = ((x >> 16) & 1u) + 0x7fffu;
    return (ushort_t)((x + r) >> 16);
}
__device__ __forceinline__ uint_t pack2(float lo, float hi) {
    return (uint_t)f2bf(lo) | ((uint_t)f2bf(hi) << 16);
}
__device__ __forceinline__ float bflo(uint_t w) { return __uint_as_float(w << 16); }
__device__ __forceinline__ float bfhi(uint_t w) { return __uint_as_float(w & 0xffff0000u); }
__device__ __forceinline__ int swz(int j) { return j ^ ((j >> 3) & 7); }

__device__ __forceinline__ uint4 cvt8(float4 f0, float4 f1) {
    uint4 o;
    o.x = pack2(f0.x, f0.y); o.y = pack2(f0.z, f0.w);
    o.z = pack2(f1.x, f1.y); o.w = pack2(f1.z, f1.w);
    return o;
}
__device__ __forceinline__ float dot8(uint4 w, float4 e0, float4 e1, float acc) {
    acc = fmaf(bflo(w.x), e0.x, acc); acc = fmaf(bfhi(w.x), e0.y, acc);
    acc = fmaf(bflo(w.y), e0.z, acc); acc = fmaf(bfhi(w.y), e0.w, acc);
    acc = fmaf(bflo(w.z), e1.x, acc); acc = fmaf(bfhi(w.z), e1.y, acc);
    acc = fmaf(bflo(w.w), e1.z, acc); acc = fmaf(bfhi(w.w), e1.w, acc);
    return acc;
}

struct KArgs {
    const float *x, *u, *C1, *D11, *D12, *Lam, *F, *B1, *B2, *E, *C2, *D21, *D22;
    const float *bv, *bx, *bu;
    const int* t;
    float* yout; float* xout;
    float *epsA, *epsB, *q, *y0, *b, *xa, *xb;
    int* flags;
};

// Flag-array grid barrier: arrival = ONE relaxed store to own slot (no RMW
// contention); wait = wave 0 polls all 256 slots (4 loads/lane) + __all.
// No acquire/release fences: data coherence comes from sc1 (agent-scope
// relaxed atomic) ops on the shared vectors; __syncthreads drains vmcnt for
// every wave before thread 0 signals arrival.
__device__ __forceinline__ void gsync(int* flags, int bar) {
    __syncthreads();
    if (threadIdx.x < 64) {
        if (threadIdx.x == 0)
            ASTOREI(&flags[blockIdx.x], bar);
        const int l = threadIdx.x;
        for (;;) {
            int m0 = ALOADI(&flags[l]);
            int m1 = ALOADI(&flags[l + 64]);
            int m2 = ALOADI(&flags[l + 128]);
            int m3 = ALOADI(&flags[l + 192]);
            int mn = m0 < m1 ? m0 : m1;
            int mn2 = m2 < m3 ? m2 : m3;
            mn = mn < mn2 ? mn : mn2;
            if (__all(mn >= bar)) break;
            __builtin_amdgcn_s_sleep(4);
        }
    }
    __syncthreads();
}

__global__ void init_sync(int* flags) {
    flags[threadIdx.x] = 0;   // launched with 256 threads
}

__device__ __forceinline__ float dot_f32(const float* __restrict__ Mrow,
                                         const float* __restrict__ v,
                                         int n, int lane) {
    const float4* Mr = reinterpret_cast<const float4*>(Mrow);
    const float4* V  = reinterpret_cast<const float4*>(v);
    float acc = 0.f;
    int nv = n >> 2;
    for (int c = lane; c < nv; c += 64) {
        float4 m = Mr[c], vv = V[c];
        acc = fmaf(m.x, vv.x, acc); acc = fmaf(m.y, vv.y, acc);
        acc = fmaf(m.z, vv.z, acc); acc = fmaf(m.w, vv.w, acc);
    }
    return acc;
}

// dot of fp32 global row against LDS-staged swizzled vector (nf4 float4)
__device__ __forceinline__ float dot_lds_f32(const float* __restrict__ Mrow,
                                             const float4* evec, int nf4, int lane) {
    const float4* Mr = reinterpret_cast<const float4*>(Mrow);
    float acc = 0.f;
    for (int c = lane; c < nf4; c += 64) {
        float4 m = Mr[c];
        float4 e = evec[swz(c)];
        acc = fmaf(m.x, e.x, acc); acc = fmaf(m.y, e.y, acc);
        acc = fmaf(m.z, e.z, acc); acc = fmaf(m.w, e.w, acc);
    }
    return acc;
}

__global__ __launch_bounds__(NTHREADS, 2) void fused_kernel(KArgs A) {
    const int tid  = threadIdx.x;
    const int lane = tid & 63;
    const int warp = tid >> 6;
    const int W    = blockIdx.x * 8 + warp;       // 0..2047
    const int rowA = W;                            // short D11 row (<2048 cols)
    const int rowB = (LL - 1) - W;                 // long D11 row; lenA+lenB = 4095

    __shared__ float4 evec[1024];                  // 16 KB staging buffer
    int bar = 0;
    const float decay = __powf(0.95f, (float)(*A.t));

    // ------- Phase A: one-shot matrix conversions into REGISTERS + GEMVs -----
    uint4 ra[4], rb[8], gr[4];
    {
        const int nhA = (rowA + 7) >> 3;           // uint4-chunks covering [0,rowA)
        const int nhB = (rowB + 7) >> 3;
        const float4* DrA = reinterpret_cast<const float4*>(A.D11 + (size_t)rowA * LL);
        const float4* DrB = reinterpret_cast<const float4*>(A.D11 + (size_t)rowB * LL);
        const float4* Er  = reinterpret_cast<const float4*>(A.E  + (size_t)W * NN);
#pragma unroll
        for (int kk = 0; kk < 4; ++kk) {
            int c = kk * 64 + lane;
            ra[kk] = make_uint4(0u, 0u, 0u, 0u);
            if (c < nhA) ra[kk] = cvt8(DrA[2 * c], DrA[2 * c + 1]);
        }
#pragma unroll
        for (int kk = 0; kk < 8; ++kk) {
            int c = kk * 64 + lane;
            rb[kk] = make_uint4(0u, 0u, 0u, 0u);
            if (c < nhB) rb[kk] = cvt8(DrB[2 * c], DrB[2 * c + 1]);
        }
#pragma unroll
        for (int kk = 0; kk < 4; ++kk) {           // G = I - E, row W, bf16
            int c = kk * 64 + lane;                // cols 8c..8c+7 (c < 256 always)
            float4 f0 = Er[2 * c], f1 = Er[2 * c + 1];
            int g0 = 8 * c;
            float e[8] = {f0.x, f0.y, f0.z, f0.w, f1.x, f1.y, f1.z, f1.w};
            uint_t wd[4];
#pragma unroll
            for (int j2 = 0; j2 < 4; ++j2) {
                float glo = ((g0 + 2 * j2)     == W ? 1.f : 0.f) - e[2 * j2];
                float ghi = ((g0 + 2 * j2 + 1) == W ? 1.f : 0.f) - e[2 * j2 + 1];
                wd[j2] = pack2(glo, ghi);
            }
            gr[kk] = make_uint4(wd[0], wd[1], wd[2], wd[3]);
        }
    }

    float aA, lamA, aB, lamB;
    {   // a rows for rowA and rowB
        float acc = dot_f32(A.C1 + (size_t)rowA * NN, A.x, NN, lane)
                  + dot_f32(A.D12 + (size_t)rowA * MM, A.u, MM, lane);
        acc = wave_reduce_sum(acc);
        lamA = A.Lam[rowA];
        aA = fmaf(decay, A.bv[rowA], acc);
        if (lane == 0) ASTOREF(&A.epsA[rowA], tanhf(aA / lamA));

        acc = dot_f32(A.C1 + (size_t)rowB * NN, A.x, NN, lane)
            + dot_f32(A.D12 + (size_t)rowB * MM, A.u, MM, lane);
        acc = wave_reduce_sum(acc);
        lamB = A.Lam[rowB];
        aB = fmaf(decay, A.bv[rowB], acc);
        if (lane == 0) ASTOREF(&A.epsA[rowB], tanhf(aB / lamB));
    }
    {   // q row W (NN == NWAVES, exact 1:1)
        float acc = dot_f32(A.F + (size_t)W * NN, A.x, NN, lane)
                  + dot_f32(A.B2 + (size_t)W * MM, A.u, MM, lane);
        acc = wave_reduce_sum(acc);
        if (lane == 0) ASTOREF(&A.q[W], fmaf(decay, A.bx[W], acc));
    }
    if (W < PP) {   // y0 row W
        float acc = dot_f32(A.C2 + (size_t)W * NN, A.x, NN, lane)
                  + dot_f32(A.D22 + (size_t)W * MM, A.u, MM, lane);
        acc = wave_reduce_sum(acc);
        if (lane == 0) ASTOREF(&A.y0[W], fmaf(decay, A.bu[W], acc));
    }
    gsync(A.flags, ++bar);

    // ------- Phase B: tanh-Jacobi sweeps, D11 rows in registers -------------
    for (int s = 0; s < SWEEPS; ++s) {
        const float* ein = (s & 1) ? A.epsB : A.epsA;
        float*      eout = (s & 1) ? A.epsA : A.epsB;
        for (int j = tid; j < 1024; j += NTHREADS) {   // stage 4096 floats
            float4 v;
            v.x = ALOADF(ein + 4 * j);     v.y = ALOADF(ein + 4 * j + 1);
            v.z = ALOADF(ein + 4 * j + 2); v.w = ALOADF(ein + 4 * j + 3);
            evec[swz(j)] = v;
        }
        __syncthreads();
        float sA = 0.f, sB = 0.f;
#pragma unroll
        for (int kk = 0; kk < 4; ++kk) {
            int c = kk * 64 + lane;
            float4 e0 = evec[swz(2 * c)], e1 = evec[swz(2 * c + 1)];
            sA = dot8(ra[kk], e0, e1, sA);
            sB = dot8(rb[kk], e0, e1, sB);
        }
#pragma unroll
        for (int kk = 4; kk < 8; ++kk) {
            int c = kk * 64 + lane;
            float4 e0 = evec[swz(2 * c)], e1 = evec[swz(2 * c + 1)];
            sB = dot8(rb[kk], e0, e1, sB);
        }
        sA = wave_reduce_sum(sA);
        sB = wave_reduce_sum(sB);
        if (lane == 0) {
            ASTOREF(&eout[rowA], tanhf((aA + sA) / lamA));
            ASTOREF(&eout[rowB], tanhf((aB + sB) / lamB));
        }
        gsync(A.flags, ++bar);
    }
    const float* eps = (SWEEPS & 1) ? A.epsB : A.epsA;

    // ------- Phase C: y = D21 eps + y0 ; b = B1 eps + q ----------------------
    for (int j = tid; j < 1024; j += NTHREADS) {       // stage final eps
        float4 v;
        v.x = ALOADF(eps + 4 * j);     v.y = ALOADF(eps + 4 * j + 1);
        v.z = ALOADF(eps + 4 * j + 2); v.w = ALOADF(eps + 4 * j + 3);
        evec[swz(j)] = v;
    }
    __syncthreads();
    {
        float acc = dot_lds_f32(A.B1 + (size_t)W * LL, evec, 1024, lane);
        acc = wave_reduce_sum(acc);
        if (lane == 0) ASTOREF(&A.b[W], ALOADF(&A.q[W]) + acc);
    }
    if (W < PP) {
        float acc = dot_lds_f32(A.D21 + (size_t)W * LL, evec, 1024, lane);
        acc = wave_reduce_sum(acc);
        if (lane == 0) A.yout[W] = ALOADF(&A.y0[W]) + acc;
    }
    gsync(A.flags, ++bar);

    // ------- Phase D: Richardson x <- b + G x, G row W in registers ----------
    const float b_r = ALOADF(&A.b[W]);
    for (int k = 0; k < RICH; ++k) {
        const float* xin = (k == 0) ? A.b : ((k & 1) ? A.xa : A.xb);
        float*       xo  = (k == RICH - 1) ? A.xout : ((k & 1) ? A.xb : A.xa);
        for (int j = tid; j < 512; j += NTHREADS) {    // stage 2048 floats
            float4 v;
            v.x = ALOADF(xin + 4 * j);     v.y = ALOADF(xin + 4 * j + 1);
            v.z = ALOADF(xin + 4 * j + 2); v.w = ALOADF(xin + 4 * j + 3);
            evec[swz(j)] = v;
        }
        __syncthreads();
        float acc = 0.f;
#pragma unroll
        for (int kk = 0; kk < 4; ++kk) {
            int c = kk * 64 + lane;
            float4 e0 = evec[swz(2 * c)], e1 = evec[swz(2 * c + 1)];
            acc = dot8(gr[kk], e0, e1, acc);
        }
        acc = wave_reduce_sum(acc);
        if (lane == 0) {
            float val = b_r + acc;
            if (k == RICH - 1) xo[W] = val;            // d_out: plain store
            else               ASTOREF(&xo[W], val);
        }
        if (k < RICH - 1) gsync(A.flags, ++bar);
    }
}

extern "C" void kernel_launch(void* const* d_in, const int* in_sizes, int n_in,
                              void* d_out, int out_size, void* d_ws, size_t ws_size,
                              hipStream_t stream) {
    KArgs A;
    A.x   = (const float*)d_in[0];
    A.u   = (const float*)d_in[1];
    A.C1  = (const float*)d_in[2];
    A.D11 = (const float*)d_in[3];
    A.D12 = (const float*)d_in[4];
    A.Lam = (const float*)d_in[5];
    A.F   = (const float*)d_in[6];
    A.B1  = (const float*)d_in[7];
    A.B2  = (const float*)d_in[8];
    A.E   = (const float*)d_in[9];
    A.C2  = (const float*)d_in[10];
    A.D21 = (const float*)d_in[11];
    A.D22 = (const float*)d_in[12];
    A.bv  = (const float*)d_in[13];
    A.bx  = (const float*)d_in[14];
    A.bu  = (const float*)d_in[15];
    A.t   = (const int*)d_in[16];
    A.yout = (float*)d_out;
    A.xout = (float*)d_out + PP;

    float* vecs = (float*)d_ws;
    A.epsA = vecs;                // 4096
    A.epsB = vecs + 4096;         // 4096
    A.q    = vecs + 8192;         // 2048
    A.y0   = vecs + 10240;        // 512
    A.b    = vecs + 10752;        // 2048
    A.xa   = vecs + 12800;        // 2048
    A.xb   = vecs + 14848;        // 2048
    A.flags = (int*)(vecs + 16896);  // 256 ints

    init_sync<<<1, 256, 0, stream>>>(A.flags);

    void* params[] = { &A };
    hipLaunchCooperativeKernel((const void*)fused_kernel, dim3(NBLOCKS),
                               dim3(NTHREADS), params, 0, stream);
}

// Round 11
// 150.315 us; speedup vs baseline: 5.1863x; 1.3252x over previous
//
#include <hip/hip_runtime.h>

// Problem constants: N=2048, L=4096, M=512, P=512
#define NN 2048
#define LL 4096
#define MM 512
#define PP 512

#define NBLOCKS 256
#define NTHREADS 512
#define SWEEPS 13              // tanh-Jacobi sweeps after eps0 = tanh(a/Lam)
#define RICH 10                // Richardson iterations for E x = b

typedef unsigned short ushort_t;
typedef unsigned int   uint_t;
typedef unsigned long long ull_t;

__device__ __forceinline__ float wave_reduce_sum(float v) {
#pragma unroll
    for (int off = 32; off > 0; off >>= 1) v += __shfl_xor(v, off, 64);
    return v;
}

__device__ __forceinline__ ushort_t f2bf(float f) {  // RNE float->bf16
    uint_t x = __float_as_uint(f);
    uint_t r = ((x >> 16) & 1u) + 0x7fffu;
    return (ushort_t)((x + r) >> 16);
}
__device__ __forceinline__ uint_t pack2(float lo, float hi) {
    return (uint_t)f2bf(lo) | ((uint_t)f2bf(hi) << 16);
}
__device__ __forceinline__ float bflo(uint_t w) { return __uint_as_float(w << 16); }
__device__ __forceinline__ float bfhi(uint_t w) { return __uint_as_float(w & 0xffff0000u); }
__device__ __forceinline__ int swz(int j) { return j ^ ((j >> 3) & 7); }

__device__ __forceinline__ uint4 cvt8(float4 f0, float4 f1) {
    uint4 o;
    o.x = pack2(f0.x, f0.y); o.y = pack2(f0.z, f0.w);
    o.z = pack2(f1.x, f1.y); o.w = pack2(f1.z, f1.w);
    return o;
}
__device__ __forceinline__ float dot8(uint4 w, float4 e0, float4 e1, float acc) {
    acc = fmaf(bflo(w.x), e0.x, acc); acc = fmaf(bfhi(w.x), e0.y, acc);
    acc = fmaf(bflo(w.y), e0.z, acc); acc = fmaf(bfhi(w.y), e0.w, acc);
    acc = fmaf(bflo(w.z), e1.x, acc); acc = fmaf(bfhi(w.z), e1.y, acc);
    acc = fmaf(bflo(w.w), e1.z, acc); acc = fmaf(bfhi(w.w), e1.w, acc);
    return acc;
}

// Tagged 8-byte publish: {float value (lo), int tag (hi)} in ONE relaxed
// agent-scope atomic — value and tag move atomically, no fence needed.
// This primitive (compiler-generated agent atomics) is the one PROVEN
// cross-XCD coherent by rounds 7/8.
__device__ __forceinline__ void tstore(float2* p, float v, int tag) {
    ull_t pk = (ull_t)__float_as_uint(v) | ((ull_t)(uint_t)tag << 32);
    __hip_atomic_store((ull_t*)p, pk, __ATOMIC_RELAXED, __HIP_MEMORY_SCOPE_AGENT);
}

// Stage a tagged vector (NENT entries) into LDS (values only, float4-swizzled
// layout: evec[swz(j)] holds entries 4j..4j+3). Each thread polls its K =
// NENT/512 interleaved entries (coalesced: entry = tid + k*512) until all
// carry tag >= want. Determinism: while any block still polls for tag s, no
// producer can have written s+2 to this buffer (it would first need this
// block's s-output), and this buffer's tags have fixed parity, so every
// accepted entry has tag exactly s.
template<int NENT>
__device__ __forceinline__ void stage_vec(const float2* buf, int want,
                                          float* ev, int tid) {
    constexpr int K = NENT / 512;
    const ull_t* p = reinterpret_cast<const ull_t*>(buf);
    ull_t u[K];
    for (;;) {
        int tmin = 0x7fffffff;
#pragma unroll
        for (int k = 0; k < K; ++k) {
            u[k] = __hip_atomic_load(p + tid + k * 512, __ATOMIC_RELAXED,
                                     __HIP_MEMORY_SCOPE_AGENT);
            tmin = min(tmin, (int)(u[k] >> 32));
        }
        if (tmin >= want) break;
        __builtin_amdgcn_s_sleep(1);
    }
#pragma unroll
    for (int k = 0; k < K; ++k) {
        int e = tid + k * 512;                      // entry index
        ev[(swz(e >> 2) << 2) | (e & 3)] = __uint_as_float((uint_t)u[k]);
    }
}

struct KArgs {
    const float *x, *u, *C1, *D11, *D12, *Lam, *F, *B1, *B2, *E, *C2, *D21, *D22;
    const float *bv, *bx, *bu;
    const int* t;
    float* yout; float* xout;
    float2 *epsA, *epsB, *bT, *xaT, *xbT;   // tagged vectors
};

// Clears all tagged buffers (14336 x 8B) every call — graph-replay safe.
__global__ __launch_bounds__(512) void clear_tags(ull_t* p) {
    p[blockIdx.x * 512 + threadIdx.x] = 0ull;
}

__device__ __forceinline__ float dot_f32(const float* __restrict__ Mrow,
                                         const float* __restrict__ v,
                                         int n, int lane) {
    const float4* Mr = reinterpret_cast<const float4*>(Mrow);
    const float4* V  = reinterpret_cast<const float4*>(v);
    float acc = 0.f;
    int nv = n >> 2;
    for (int c = lane; c < nv; c += 64) {
        float4 m = Mr[c], vv = V[c];
        acc = fmaf(m.x, vv.x, acc); acc = fmaf(m.y, vv.y, acc);
        acc = fmaf(m.z, vv.z, acc); acc = fmaf(m.w, vv.w, acc);
    }
    return acc;
}

// dot of fp32 global row against LDS-staged swizzled vector (nf4 float4)
__device__ __forceinline__ float dot_lds_f32(const float* __restrict__ Mrow,
                                             const float4* evec, int nf4, int lane) {
    const float4* Mr = reinterpret_cast<const float4*>(Mrow);
    float acc = 0.f;
    for (int c = lane; c < nf4; c += 64) {
        float4 m = Mr[c];
        float4 e = evec[swz(c)];
        acc = fmaf(m.x, e.x, acc); acc = fmaf(m.y, e.y, acc);
        acc = fmaf(m.z, e.z, acc); acc = fmaf(m.w, e.w, acc);
    }
    return acc;
}

__global__ __launch_bounds__(NTHREADS, 2) void fused_kernel(KArgs A) {
    const int tid  = threadIdx.x;
    const int lane = tid & 63;
    const int warp = tid >> 6;
    const int W    = blockIdx.x * 8 + warp;        // 0..2047
    const int rowA = W;                             // short D11 row
    const int rowB = (LL - 1) - W;                  // long row; lenA+lenB=4095

    __shared__ float4 evec[1024];                   // 16 KB value staging
    float* ev = reinterpret_cast<float*>(evec);

    const float decay = __powf(0.95f, (float)(*A.t));

    // ---- Phase A1: a-rows (critical path — publish eps0 ASAP) -------------
    float aA, lamA, aB, lamB;
    {
        float acc = dot_f32(A.C1 + (size_t)rowA * NN, A.x, NN, lane)
                  + dot_f32(A.D12 + (size_t)rowA * MM, A.u, MM, lane);
        acc = wave_reduce_sum(acc);
        lamA = A.Lam[rowA];
        aA = fmaf(decay, A.bv[rowA], acc);
        if (lane == 0) tstore(&A.epsA[rowA], tanhf(aA / lamA), 1);

        acc = dot_f32(A.C1 + (size_t)rowB * NN, A.x, NN, lane)
            + dot_f32(A.D12 + (size_t)rowB * MM, A.u, MM, lane);
        acc = wave_reduce_sum(acc);
        lamB = A.Lam[rowB];
        aB = fmaf(decay, A.bv[rowB], acc);
        if (lane == 0) tstore(&A.epsA[rowB], tanhf(aB / lamB), 1);
    }

    // ---- Phase A2: q, y0 (stay in registers — same wave consumes them) ----
    float q_r, y0_r = 0.f;
    {
        float acc = dot_f32(A.F + (size_t)W * NN, A.x, NN, lane)
                  + dot_f32(A.B2 + (size_t)W * MM, A.u, MM, lane);
        acc = wave_reduce_sum(acc);
        q_r = fmaf(decay, A.bx[W], acc);
    }
    if (W < PP) {
        float acc = dot_f32(A.C2 + (size_t)W * NN, A.x, NN, lane)
                  + dot_f32(A.D22 + (size_t)W * MM, A.u, MM, lane);
        acc = wave_reduce_sum(acc);
        y0_r = fmaf(decay, A.bu[W], acc);
    }

    // ---- Phase A3: one-shot matrix conversions into registers -------------
    uint4 ra[4], rb[8], gr[4];
    {
        const int nhA = (rowA + 7) >> 3;
        const int nhB = (rowB + 7) >> 3;
        const float4* DrA = reinterpret_cast<const float4*>(A.D11 + (size_t)rowA * LL);
        const float4* DrB = reinterpret_cast<const float4*>(A.D11 + (size_t)rowB * LL);
        const float4* Er  = reinterpret_cast<const float4*>(A.E  + (size_t)W * NN);
#pragma unroll
        for (int kk = 0; kk < 4; ++kk) {
            int c = kk * 64 + lane;
            ra[kk] = make_uint4(0u, 0u, 0u, 0u);
            if (c < nhA) ra[kk] = cvt8(DrA[2 * c], DrA[2 * c + 1]);
        }
#pragma unroll
        for (int kk = 0; kk < 8; ++kk) {
            int c = kk * 64 + lane;
            rb[kk] = make_uint4(0u, 0u, 0u, 0u);
            if (c < nhB) rb[kk] = cvt8(DrB[2 * c], DrB[2 * c + 1]);
        }
#pragma unroll
        for (int kk = 0; kk < 4; ++kk) {            // G = I - E, row W, bf16
            int c = kk * 64 + lane;
            float4 f0 = Er[2 * c], f1 = Er[2 * c + 1];
            int g0 = 8 * c;
            float e[8] = {f0.x, f0.y, f0.z, f0.w, f1.x, f1.y, f1.z, f1.w};
            uint_t wd[4];
#pragma unroll
            for (int j2 = 0; j2 < 4; ++j2) {
                float glo = ((g0 + 2 * j2)     == W ? 1.f : 0.f) - e[2 * j2];
                float ghi = ((g0 + 2 * j2 + 1) == W ? 1.f : 0.f) - e[2 * j2 + 1];
                wd[j2] = pack2(glo, ghi);
            }
            gr[kk] = make_uint4(wd[0], wd[1], wd[2], wd[3]);
        }
    }

    // ---- Phase B: tanh-Jacobi sweeps — tagged dataflow, no barriers -------
    // Invariant: sweep s reads tag s from in, writes tag s+1 to out.
    for (int s = 1; s <= SWEEPS; ++s) {
        const float2* in = (s & 1) ? A.epsA : A.epsB;
        float2*      out = (s & 1) ? A.epsB : A.epsA;
        stage_vec<LL>(in, s, ev, tid);
        __syncthreads();
        float sA = 0.f, sB = 0.f;
#pragma unroll
        for (int kk = 0; kk < 4; ++kk) {
            int c = kk * 64 + lane;
            float4 e0 = evec[swz(2 * c)], e1 = evec[swz(2 * c + 1)];
            sA = dot8(ra[kk], e0, e1, sA);
            sB = dot8(rb[kk], e0, e1, sB);
        }
#pragma unroll
        for (int kk = 4; kk < 8; ++kk) {
            int c = kk * 64 + lane;
            float4 e0 = evec[swz(2 * c)], e1 = evec[swz(2 * c + 1)];
            sB = dot8(rb[kk], e0, e1, sB);
        }
        sA = wave_reduce_sum(sA);
        sB = wave_reduce_sum(sB);
        if (lane == 0) {
            tstore(&out[rowA], tanhf((aA + sA) / lamA), s + 1);
            tstore(&out[rowB], tanhf((aB + sB) / lamB), s + 1);
        }
        __syncthreads();   // LDS safe to overwrite next sweep
    }

    // ---- Phase C: y = D21 eps + y0 ; b = B1 eps + q ------------------------
    float b_r;
    {
        const float2* efin = (SWEEPS & 1) ? A.epsB : A.epsA;  // tag SWEEPS+1
        stage_vec<LL>(efin, SWEEPS + 1, ev, tid);
        __syncthreads();
        float acc = dot_lds_f32(A.B1 + (size_t)W * LL, evec, 1024, lane);
        acc = wave_reduce_sum(acc);
        b_r = q_r + acc;
        if (lane == 0) tstore(&A.bT[W], b_r, 1);
        if (W < PP) {
            float ya = dot_lds_f32(A.D21 + (size_t)W * LL, evec, 1024, lane);
            ya = wave_reduce_sum(ya);
            if (lane == 0) A.yout[W] = y0_r + ya;
        }
        __syncthreads();
    }

    // ---- Phase D: Richardson x <- b + G x, dataflow -------------------------
    // Step k reads (k==0 ? bT tag 1 : buf[(k-1)&1] tag k+1), writes buf[k&1]
    // tag k+2. Reader of step k+1 matches writer of step k by construction.
    {
        float2* buf[2] = { A.xaT, A.xbT };
        for (int k = 0; k < RICH; ++k) {
            const float2* xin = (k == 0) ? A.bT : buf[(k - 1) & 1];
            stage_vec<NN>(xin, k + 1, ev, tid);
            __syncthreads();
            float acc = 0.f;
#pragma unroll
            for (int kk = 0; kk < 4; ++kk) {
                int c = kk * 64 + lane;
                float4 e0 = evec[swz(2 * c)], e1 = evec[swz(2 * c + 1)];
                acc = dot8(gr[kk], e0, e1, acc);
            }
            acc = wave_reduce_sum(acc);
            float val = b_r + acc;
            if (lane == 0) {
                if (k == RICH - 1) A.xout[W] = val;           // final: plain store
                else tstore(&buf[k & 1][W], val, k + 2);
            }
            __syncthreads();
        }
    }
}

extern "C" void kernel_launch(void* const* d_in, const int* in_sizes, int n_in,
                              void* d_out, int out_size, void* d_ws, size_t ws_size,
                              hipStream_t stream) {
    KArgs A;
    A.x   = (const float*)d_in[0];
    A.u   = (const float*)d_in[1];
    A.C1  = (const float*)d_in[2];
    A.D11 = (const float*)d_in[3];
    A.D12 = (const float*)d_in[4];
    A.Lam = (const float*)d_in[5];
    A.F   = (const float*)d_in[6];
    A.B1  = (const float*)d_in[7];
    A.B2  = (const float*)d_in[8];
    A.E   = (const float*)d_in[9];
    A.C2  = (const float*)d_in[10];
    A.D21 = (const float*)d_in[11];
    A.D22 = (const float*)d_in[12];
    A.bv  = (const float*)d_in[13];
    A.bx  = (const float*)d_in[14];
    A.bu  = (const float*)d_in[15];
    A.t   = (const int*)d_in[16];
    A.yout = (float*)d_out;
    A.xout = (float*)d_out + PP;

    // Tagged buffers, contiguous from ws start: 14336 x 8B = 114,688 bytes
    float2* f2 = (float2*)d_ws;
    A.epsA = f2;            // 4096
    A.epsB = f2 + 4096;     // 4096
    A.bT   = f2 + 8192;     // 2048
    A.xaT  = f2 + 10240;    // 2048
    A.xbT  = f2 + 12288;    // 2048  (total 14336)

    clear_tags<<<28, 512, 0, stream>>>((ull_t*)d_ws);   // 28*512 = 14336

    void* params[] = { &A };
    hipLaunchCooperativeKernel((const void*)fused_kernel, dim3(NBLOCKS),
                               dim3(NTHREADS), params, 0, stream);
}